// Round 1
// baseline (254.193 us; speedup 1.0000x reference)
//
#include <hip/hip_runtime.h>
#include <math.h>

#define BB   16
#define NN   128
#define NCC  32
#define HH   256
#define AA   64
#define DEGN 3
#define BNR  (BB*NN)   // 2048 rows

// ---------------------------------------------------------------------------
// Kernel 1: masked mean-pool of condition vectors -> pooled [B,H]
// ---------------------------------------------------------------------------
__global__ __launch_bounds__(256) void k_pool(const float* __restrict__ cond,
                                              const float* __restrict__ cmask,
                                              float* __restrict__ pooled) {
    int b = blockIdx.x, h = threadIdx.x;
    float s = 0.f, ms = 0.f;
    for (int c = 0; c < NCC; ++c) {
        float mk = cmask[b * NCC + c];
        s  += cond[(b * NCC + c) * HH + h] * mk;
        ms += mk;
    }
    pooled[b * HH + h] = s / fmaxf(ms, 1.0f);
}

// ---------------------------------------------------------------------------
// Kernel 2: dv[d,b,:] = pooled[b,:] @ Wc[d]  (also writes dvs output)
// ---------------------------------------------------------------------------
__global__ __launch_bounds__(256) void k_dv(const float* __restrict__ pooled,
                                            const float* __restrict__ Wc,
                                            float* __restrict__ dv,
                                            float* __restrict__ dv_out) {
    int d = blockIdx.x / BB, b = blockIdx.x % BB, h = threadIdx.x;
    const float* Wd = Wc + (size_t)d * HH * HH;
    const float* pb = pooled + b * HH;
    float acc = 0.f;
    for (int k = 0; k < HH; ++k) acc += pb[k] * Wd[k * HH + h];
    int idx = (d * BB + b) * HH + h;
    dv[idx]     = acc;
    dv_out[idx] = acc;
}

// ---------------------------------------------------------------------------
// Kernel 3: hbuf[d,row,:] = gelu_tanh(x[row,:] @ W1[d] + b1[d] + dv[d,b])
// 16 rows per block, 256 cols (=H) per thread dim.
// ---------------------------------------------------------------------------
__global__ __launch_bounds__(256) void k_enc(const float* __restrict__ x,
                                             const float* __restrict__ W1,
                                             const float* __restrict__ b1,
                                             const float* __restrict__ dv,
                                             float* __restrict__ hbuf) {
    const int RT = BNR / 16;  // 128 row-tiles
    int d = blockIdx.x / RT, rt = blockIdx.x % RT;
    int row0 = rt * 16;
    int h = threadIdx.x;
    __shared__ float xs[16][HH];
    #pragma unroll
    for (int rr = 0; rr < 16; ++rr) xs[rr][h] = x[(row0 + rr) * HH + h];
    __syncthreads();

    float acc[16];
    #pragma unroll
    for (int r = 0; r < 16; ++r) acc[r] = 0.f;

    const float* Wd = W1 + (size_t)d * HH * HH;
    for (int k = 0; k < HH; k += 4) {
        float w0 = Wd[(k + 0) * HH + h], w1 = Wd[(k + 1) * HH + h];
        float w2 = Wd[(k + 2) * HH + h], w3 = Wd[(k + 3) * HH + h];
        #pragma unroll
        for (int r = 0; r < 16; ++r) {
            float4 xv = *(const float4*)&xs[r][k];
            acc[r] += xv.x * w0 + xv.y * w1 + xv.z * w2 + xv.w * w3;
        }
    }
    int b = row0 / NN;
    float add = b1[d * HH + h] + dv[(d * BB + b) * HH + h];
    #pragma unroll
    for (int r = 0; r < 16; ++r) {
        float v = acc[r] + add;
        // jax.nn.gelu default (approximate=True, tanh form)
        float u = 0.7978845608028654f * (v + 0.044715f * v * v * v);
        float g = 0.5f * v * (1.0f + tanhf(u));
        hbuf[((size_t)d * BNR + row0 + r) * HH + h] = g;
    }
}

// ---------------------------------------------------------------------------
// Kernel 4: yv[d,row,:] = (hbuf[d,row,:] @ Wlin[d] + blin[d]) * x_mask[row]
// ---------------------------------------------------------------------------
__global__ __launch_bounds__(256) void k_lin(const float* __restrict__ hbuf,
                                             const float* __restrict__ Wlin,
                                             const float* __restrict__ blin,
                                             const float* __restrict__ xmask,
                                             float* __restrict__ yv) {
    const int RT = BNR / 16;
    int d = blockIdx.x / RT, rt = blockIdx.x % RT;
    int row0 = rt * 16;
    int t = threadIdx.x;
    int a = t & 63, rg = t >> 6;  // 4 row-groups x 4 rows
    __shared__ float hs[16][HH];
    for (int e = t; e < 16 * HH; e += 256) {
        int rr = e >> 8, k = e & 255;
        hs[rr][k] = hbuf[((size_t)d * BNR + row0 + rr) * HH + k];
    }
    __syncthreads();

    const float* Wd = Wlin + (size_t)d * HH * AA;
    float acc[4] = {0.f, 0.f, 0.f, 0.f};
    for (int k = 0; k < HH; k += 4) {
        float w0 = Wd[(k + 0) * AA + a], w1 = Wd[(k + 1) * AA + a];
        float w2 = Wd[(k + 2) * AA + a], w3 = Wd[(k + 3) * AA + a];
        #pragma unroll
        for (int rr = 0; rr < 4; ++rr) {
            float4 hv = *(const float4*)&hs[rg * 4 + rr][k];
            acc[rr] += hv.x * w0 + hv.y * w1 + hv.z * w2 + hv.w * w3;
        }
    }
    float bl = blin[d * AA + a];
    #pragma unroll
    for (int rr = 0; rr < 4; ++rr) {
        int row = row0 + rg * 4 + rr;
        yv[((size_t)d * BNR + row) * AA + a] = (acc[rr] + bl) * xmask[row];
    }
}

// ---------------------------------------------------------------------------
// Kernel 5: symmetric contraction.
// out[b,x,y,z] = (P[y,z] + P[z,y]) / 4096 for each (b,x) slab, where
//   P[y,z] = sum_i (y0[x,i]*Y1[y,i] + y1[x,i]*Y0[y,i]) * Y2[z,i]
//          +        y2[x,i]*Y0[y,i]                    * Y1[z,i]
// Two K=64 phases sharing 64KB LDS (As/Bs [128][64], XOR-swizzled cols),
// 8x8 register tiles, then in-block LDS transpose for P + P^T.
// ---------------------------------------------------------------------------
__device__ __forceinline__ void mm_acc(const float* __restrict__ As,
                                       const float* __restrict__ Bs,
                                       float acc[8][8],
                                       int y0r, int z0, int sA, int sB) {
    for (int ic = 0; ic < 16; ++ic) {
        float4 a[8], bv[8];
        int ca = (ic * 4) ^ sA, cb = (ic * 4) ^ sB;
        #pragma unroll
        for (int r = 0; r < 8; ++r) a[r]  = *(const float4*)&As[(y0r + r) * 64 + ca];
        #pragma unroll
        for (int c = 0; c < 8; ++c) bv[c] = *(const float4*)&Bs[(z0 + c)  * 64 + cb];
        #pragma unroll
        for (int r = 0; r < 8; ++r) {
            #pragma unroll
            for (int c = 0; c < 8; ++c) {
                acc[r][c] += a[r].x * bv[c].x + a[r].y * bv[c].y
                           + a[r].z * bv[c].z + a[r].w * bv[c].w;
            }
        }
    }
}

__global__ __launch_bounds__(256) void k_contract(const float* __restrict__ yv,
                                                  float* __restrict__ outp) {
    __shared__ float lds[16384];      // 64KB: As(32K)+Bs(32K), reused as P[128][128]
    float* As = lds;
    float* Bs = lds + 8192;

    const int t  = threadIdx.x;
    const int bx = blockIdx.x;        // b*N + x
    const int b  = bx >> 7, xr = bx & 127;

    const float* y0p = yv + (size_t)(0 * BNR + b * NN) * AA;
    const float* y1p = yv + (size_t)(1 * BNR + b * NN) * AA;
    const float* y2p = yv + (size_t)(2 * BNR + b * NN) * AA;

    const int il = t & 63;            // i-lane: each thread only ever needs i = t&63
    const float s0 = y0p[xr * AA + il];
    const float s1 = y1p[xr * AA + il];
    const float s2 = y2p[xr * AA + il];

    const int ty = t >> 4, tz = t & 15;
    const int y0r = ty * 8, z0 = tz * 8;
    const int sA = (ty & 7) << 2, sB = (tz & 7) << 2;

    float acc[8][8];
    #pragma unroll
    for (int r = 0; r < 8; ++r)
        #pragma unroll
        for (int c = 0; c < 8; ++c) acc[r][c] = 0.f;

    const int yb = t >> 6;
    // phase 1: As = s0*Y1 + s1*Y0 ; Bs = Y2
    for (int j = 0; j < 32; ++j) {
        int yy = yb + j * 4;
        int sw = ((yy >> 3) & 7) << 2;
        As[yy * 64 + (il ^ sw)] = s0 * y1p[yy * AA + il] + s1 * y0p[yy * AA + il];
        Bs[yy * 64 + (il ^ sw)] = y2p[yy * AA + il];
    }
    __syncthreads();
    mm_acc(As, Bs, acc, y0r, z0, sA, sB);
    __syncthreads();
    // phase 2: As = s2*Y0 ; Bs = Y1
    for (int j = 0; j < 32; ++j) {
        int yy = yb + j * 4;
        int sw = ((yy >> 3) & 7) << 2;
        As[yy * 64 + (il ^ sw)] = s2 * y0p[yy * AA + il];
        Bs[yy * 64 + (il ^ sw)] = y1p[yy * AA + il];
    }
    __syncthreads();
    mm_acc(As, Bs, acc, y0r, z0, sA, sB);
    __syncthreads();

    // write P into lds as [128][128]
    #pragma unroll
    for (int r = 0; r < 8; ++r) {
        float4 w0 = make_float4(acc[r][0], acc[r][1], acc[r][2], acc[r][3]);
        float4 w1 = make_float4(acc[r][4], acc[r][5], acc[r][6], acc[r][7]);
        *(float4*)&lds[(y0r + r) * 128 + z0    ] = w0;
        *(float4*)&lds[(y0r + r) * 128 + z0 + 4] = w1;
    }
    __syncthreads();
    // acc[r][c] += P[z0+c][y0r+r]   (the P^T term)
    #pragma unroll
    for (int c = 0; c < 8; ++c) {
        float4 p0 = *(const float4*)&lds[(z0 + c) * 128 + y0r    ];
        float4 p1 = *(const float4*)&lds[(z0 + c) * 128 + y0r + 4];
        acc[0][c] += p0.x; acc[1][c] += p0.y; acc[2][c] += p0.z; acc[3][c] += p0.w;
        acc[4][c] += p1.x; acc[5][c] += p1.y; acc[6][c] += p1.z; acc[7][c] += p1.w;
    }
    const float inv = 1.0f / 4096.0f;  // weights_scale = sqrt(256)^3
    float* osl = outp + (size_t)bx * (NN * NN);
    #pragma unroll
    for (int r = 0; r < 8; ++r) {
        float4 w0 = make_float4(acc[r][0] * inv, acc[r][1] * inv,
                                acc[r][2] * inv, acc[r][3] * inv);
        float4 w1 = make_float4(acc[r][4] * inv, acc[r][5] * inv,
                                acc[r][6] * inv, acc[r][7] * inv);
        *(float4*)&osl[(y0r + r) * NN + z0    ] = w0;
        *(float4*)&osl[(y0r + r) * NN + z0 + 4] = w1;
    }
}

// ---------------------------------------------------------------------------
extern "C" void kernel_launch(void* const* d_in, const int* in_sizes, int n_in,
                              void* d_out, int out_size, void* d_ws, size_t ws_size,
                              hipStream_t stream) {
    const float* x     = (const float*)d_in[0];
    const float* xmask = (const float*)d_in[1];
    const float* cond  = (const float*)d_in[2];
    const float* cmask = (const float*)d_in[3];
    const float* W1    = (const float*)d_in[4];
    const float* b1    = (const float*)d_in[5];
    const float* Wc    = (const float*)d_in[6];
    const float* Wlin  = (const float*)d_in[7];
    const float* blin  = (const float*)d_in[8];

    float* out = (float*)d_out;
    float* ws  = (float*)d_ws;

    // ws layout (floats)
    float* pooled = ws;                        // 16*256        = 4096
    float* dv     = ws + 4096;                 // 3*16*256      = 12288
    float* hbuf   = ws + 16384;                // 3*2048*256    = 1572864
    float* yv     = ws + 16384 + 1572864;      // 3*2048*64     = 393216
    float* dv_out = out + (size_t)BB * NN * NN * NN;  // dvs output region

    k_pool    <<<dim3(BB),            dim3(256), 0, stream>>>(cond, cmask, pooled);
    k_dv      <<<dim3(DEGN * BB),     dim3(256), 0, stream>>>(pooled, Wc, dv, dv_out);
    k_enc     <<<dim3(DEGN * (BNR/16)), dim3(256), 0, stream>>>(x, W1, b1, dv, hbuf);
    k_lin     <<<dim3(DEGN * (BNR/16)), dim3(256), 0, stream>>>(hbuf, Wlin, blin, xmask, yv);
    k_contract<<<dim3(BNR),           dim3(256), 0, stream>>>(yv, out);
}

// Round 2
// 113.184 us; speedup vs baseline: 2.2458x; 2.2458x over previous
//
#include <hip/hip_runtime.h>
#include <hip/hip_bf16.h>
#include <math.h>
#include <string.h>

#define BB   16
#define NN   128
#define NCC  32
#define HH   256
#define AA   64
#define DEGN 3
#define BNR  (BB*NN)   // 2048 rows

typedef __bf16 bf16x8 __attribute__((ext_vector_type(8)));
typedef float  f32x4  __attribute__((ext_vector_type(4)));

// ---------------------------------------------------------------------------
// Kernel 1: masked mean-pool of condition vectors -> pooled [B,H]
// ---------------------------------------------------------------------------
__global__ __launch_bounds__(256) void k_pool(const float* __restrict__ cond,
                                              const float* __restrict__ cmask,
                                              float* __restrict__ pooled) {
    int b = blockIdx.x, h = threadIdx.x;
    float s = 0.f, ms = 0.f;
    for (int c = 0; c < NCC; ++c) {
        float mk = cmask[b * NCC + c];
        s  += cond[(b * NCC + c) * HH + h] * mk;
        ms += mk;
    }
    pooled[b * HH + h] = s / fmaxf(ms, 1.0f);
}

// ---------------------------------------------------------------------------
// Kernel 2: dv[d,b,:] = pooled[b,:] @ Wc[d]  (also writes dvs output)
// ---------------------------------------------------------------------------
__global__ __launch_bounds__(256) void k_dv(const float* __restrict__ pooled,
                                            const float* __restrict__ Wc,
                                            float* __restrict__ dv,
                                            float* __restrict__ dv_out) {
    int d = blockIdx.x / BB, b = blockIdx.x % BB, h = threadIdx.x;
    const float* Wd = Wc + (size_t)d * HH * HH;
    const float* pb = pooled + b * HH;
    float acc = 0.f;
    for (int k = 0; k < HH; ++k) acc += pb[k] * Wd[k * HH + h];
    int idx = (d * BB + b) * HH + h;
    dv[idx]     = acc;
    dv_out[idx] = acc;
}

// ---------------------------------------------------------------------------
// Kernel 3: hbuf[d,row,:] = gelu_tanh(x[row,:] @ W1[d] + b1[d] + dv[d,b])
// ---------------------------------------------------------------------------
__global__ __launch_bounds__(256) void k_enc(const float* __restrict__ x,
                                             const float* __restrict__ W1,
                                             const float* __restrict__ b1,
                                             const float* __restrict__ dv,
                                             float* __restrict__ hbuf) {
    const int RT = BNR / 16;  // 128 row-tiles
    int d = blockIdx.x / RT, rt = blockIdx.x % RT;
    int row0 = rt * 16;
    int h = threadIdx.x;
    __shared__ float xs[16][HH];
    #pragma unroll
    for (int rr = 0; rr < 16; ++rr) xs[rr][h] = x[(row0 + rr) * HH + h];
    __syncthreads();

    float acc[16];
    #pragma unroll
    for (int r = 0; r < 16; ++r) acc[r] = 0.f;

    const float* Wd = W1 + (size_t)d * HH * HH;
    for (int k = 0; k < HH; k += 4) {
        float w0 = Wd[(k + 0) * HH + h], w1 = Wd[(k + 1) * HH + h];
        float w2 = Wd[(k + 2) * HH + h], w3 = Wd[(k + 3) * HH + h];
        #pragma unroll
        for (int r = 0; r < 16; ++r) {
            float4 xv = *(const float4*)&xs[r][k];
            acc[r] += xv.x * w0 + xv.y * w1 + xv.z * w2 + xv.w * w3;
        }
    }
    int b = row0 / NN;
    float add = b1[d * HH + h] + dv[(d * BB + b) * HH + h];
    #pragma unroll
    for (int r = 0; r < 16; ++r) {
        float v = acc[r] + add;
        float u = 0.7978845608028654f * (v + 0.044715f * v * v * v);
        float g = 0.5f * v * (1.0f + tanhf(u));
        hbuf[((size_t)d * BNR + row0 + r) * HH + h] = g;
    }
}

// ---------------------------------------------------------------------------
// Kernel 4: yv[d,row,:] = (hbuf[d,row,:] @ Wlin[d] + blin[d]) * x_mask[row]
// ---------------------------------------------------------------------------
__global__ __launch_bounds__(256) void k_lin(const float* __restrict__ hbuf,
                                             const float* __restrict__ Wlin,
                                             const float* __restrict__ blin,
                                             const float* __restrict__ xmask,
                                             float* __restrict__ yv) {
    const int RT = BNR / 16;
    int d = blockIdx.x / RT, rt = blockIdx.x % RT;
    int row0 = rt * 16;
    int t = threadIdx.x;
    int a = t & 63, rg = t >> 6;
    __shared__ float hs[16][HH];
    for (int e = t; e < 16 * HH; e += 256) {
        int rr = e >> 8, k = e & 255;
        hs[rr][k] = hbuf[((size_t)d * BNR + row0 + rr) * HH + k];
    }
    __syncthreads();

    const float* Wd = Wlin + (size_t)d * HH * AA;
    float acc[4] = {0.f, 0.f, 0.f, 0.f};
    for (int k = 0; k < HH; k += 4) {
        float w0 = Wd[(k + 0) * AA + a], w1 = Wd[(k + 1) * AA + a];
        float w2 = Wd[(k + 2) * AA + a], w3 = Wd[(k + 3) * AA + a];
        #pragma unroll
        for (int rr = 0; rr < 4; ++rr) {
            float4 hv = *(const float4*)&hs[rg * 4 + rr][k];
            acc[rr] += hv.x * w0 + hv.y * w1 + hv.z * w2 + hv.w * w3;
        }
    }
    float bl = blin[d * AA + a];
    #pragma unroll
    for (int rr = 0; rr < 4; ++rr) {
        int row = row0 + rg * 4 + rr;
        yv[((size_t)d * BNR + row) * AA + a] = (acc[rr] + bl) * xmask[row];
    }
}

// ---------------------------------------------------------------------------
// Kernel 5: symmetric contraction via bf16 MFMA, transpose-free.
// out*4096 = A'B'^T + B'A'^T  (= P + P^T), computed as U V^T with
// U=[A'|B'], V=[B'|A'] over K=256; so the second K-half just swaps which
// LDS buffer feeds the a/b operands. No f32 P transpose through LDS.
//   A'[r][k<64]  = s0[k]*Y1[r,k] + s1[k]*Y0[r,k];  A'[r][64+i] = s2[i]*Y0[r,i]
//   B'[r][k<64]  = Y2[r,k];                         B'[r][64+i] = Y1[r,i]
// LDS: two bf16 [128][128] tiles (32KB each), XOR-swizzled (byte ^= (row&7)<<4).
// ---------------------------------------------------------------------------
__device__ __forceinline__ unsigned int pk2(float lo, float hi) {
    __hip_bfloat162 h2 = __float22bfloat162_rn(make_float2(lo, hi));
    unsigned int u;
    memcpy(&u, &h2, 4);
    return u;
}

__device__ __forceinline__ float rdlane(float v, int k) {
    return __uint_as_float(__builtin_amdgcn_readlane(__float_as_uint(v), k));
}

__device__ __forceinline__ void store_chunk(char* base, int r, int c, const float f[8]) {
    uint4 u;
    u.x = pk2(f[0], f[1]);
    u.y = pk2(f[2], f[3]);
    u.z = pk2(f[4], f[5]);
    u.w = pk2(f[6], f[7]);
    int off = r * 256 + ((c * 16) ^ ((r & 7) << 4));
    *(uint4*)(base + off) = u;
}

__global__ __launch_bounds__(256) void k_contract(const float* __restrict__ yv,
                                                  float* __restrict__ outp) {
    __shared__ __align__(16) char lds[65536];  // A': [0,32K), B': [32K,64K)
    char* Albs = lds;
    char* Blbs = lds + 32768;

    const int t  = threadIdx.x;
    const int bx = blockIdx.x;            // b*N + x
    const int b  = bx >> 7, xr = bx & 127;

    const float* y0p = yv + (size_t)(0 * BNR + b * NN) * AA;
    const float* y1p = yv + (size_t)(1 * BNR + b * NN) * AA;
    const float* y2p = yv + (size_t)(2 * BNR + b * NN) * AA;

    const int lane = t & 63;
    // per-lane s values (each wave holds the full 64-vector across its lanes)
    const float s0 = y0p[xr * AA + lane];
    const float s1 = y1p[xr * AA + lane];
    const float s2 = y2p[xr * AA + lane];

    // ---- staging: waves 0-1 build A' rows, waves 2-3 build B' rows ----
    const int r = t & 127;
    if (t < 128) {
        const float* Y0r = y0p + r * AA;
        const float* Y1r = y1p + r * AA;
        #pragma unroll
        for (int c = 0; c < 8; ++c) {          // k = c*8 .. c*8+7
            float f[8];
            #pragma unroll
            for (int j = 0; j < 8; ++j) {
                int k = c * 8 + j;
                f[j] = rdlane(s0, k) * Y1r[k] + rdlane(s1, k) * Y0r[k];
            }
            store_chunk(Albs, r, c, f);
        }
        #pragma unroll
        for (int c = 0; c < 8; ++c) {          // k = 64 + c*8 ..
            float f[8];
            #pragma unroll
            for (int j = 0; j < 8; ++j) {
                int k = c * 8 + j;
                f[j] = rdlane(s2, k) * Y0r[k];
            }
            store_chunk(Albs, r, c + 8, f);
        }
    } else {
        const float* Y2r = y2p + r * AA;
        const float* Y1r = y1p + r * AA;
        #pragma unroll
        for (int c = 0; c < 8; ++c) {
            float f[8];
            #pragma unroll
            for (int j = 0; j < 8; ++j) f[j] = Y2r[c * 8 + j];
            store_chunk(Blbs, r, c, f);
        }
        #pragma unroll
        for (int c = 0; c < 8; ++c) {
            float f[8];
            #pragma unroll
            for (int j = 0; j < 8; ++j) f[j] = Y1r[c * 8 + j];
            store_chunk(Blbs, r, c + 8, f);
        }
    }
    __syncthreads();

    // ---- MFMA main loop: each wave computes a 64x64 output sub-tile ----
    const int wid = t >> 6;
    const int wy = (wid >> 1) * 64, wz = (wid & 1) * 64;
    const int rl = lane & 15, hi = lane >> 4;

    f32x4 acc[4][4];
    #pragma unroll
    for (int mi = 0; mi < 4; ++mi)
        #pragma unroll
        for (int ni = 0; ni < 4; ++ni) {
            f32x4 z = {0.f, 0.f, 0.f, 0.f};
            acc[mi][ni] = z;
        }

    #pragma unroll
    for (int half = 0; half < 2; ++half) {
        const char* Ua = half ? Blbs : Albs;   // a-operand rows (y-range)
        const char* Vb = half ? Albs : Blbs;   // b-operand rows (z-range)
        #pragma unroll
        for (int ks = 0; ks < 4; ++ks) {
            bf16x8 af[4], bf[4];
            #pragma unroll
            for (int mi = 0; mi < 4; ++mi) {
                int row = wy + mi * 16 + rl;
                af[mi] = *(const bf16x8*)(Ua + row * 256 +
                          ((ks * 64 + hi * 16) ^ ((row & 7) << 4)));
            }
            #pragma unroll
            for (int ni = 0; ni < 4; ++ni) {
                int row = wz + ni * 16 + rl;
                bf[ni] = *(const bf16x8*)(Vb + row * 256 +
                          ((ks * 64 + hi * 16) ^ ((row & 7) << 4)));
            }
            #pragma unroll
            for (int mi = 0; mi < 4; ++mi)
                #pragma unroll
                for (int ni = 0; ni < 4; ++ni)
                    acc[mi][ni] = __builtin_amdgcn_mfma_f32_16x16x32_bf16(
                        af[mi], bf[ni], acc[mi][ni], 0, 0, 0);
        }
    }

    // ---- epilogue: scale and store (C/D layout: col=lane&15, row=hi*4+j) ----
    const float inv = 1.0f / 4096.0f;
    float* osl = outp + (size_t)bx * (NN * NN);
    #pragma unroll
    for (int mi = 0; mi < 4; ++mi) {
        #pragma unroll
        for (int ni = 0; ni < 4; ++ni) {
            int col   = wz + ni * 16 + rl;
            int rbase = wy + mi * 16 + hi * 4;
            #pragma unroll
            for (int j = 0; j < 4; ++j)
                osl[(rbase + j) * NN + col] = acc[mi][ni][j] * inv;
        }
    }
}

// ---------------------------------------------------------------------------
extern "C" void kernel_launch(void* const* d_in, const int* in_sizes, int n_in,
                              void* d_out, int out_size, void* d_ws, size_t ws_size,
                              hipStream_t stream) {
    const float* x     = (const float*)d_in[0];
    const float* xmask = (const float*)d_in[1];
    const float* cond  = (const float*)d_in[2];
    const float* cmask = (const float*)d_in[3];
    const float* W1    = (const float*)d_in[4];
    const float* b1    = (const float*)d_in[5];
    const float* Wc    = (const float*)d_in[6];
    const float* Wlin  = (const float*)d_in[7];
    const float* blin  = (const float*)d_in[8];

    float* out = (float*)d_out;
    float* ws  = (float*)d_ws;

    float* pooled = ws;                        // 16*256
    float* dv     = ws + 4096;                 // 3*16*256
    float* hbuf   = ws + 16384;                // 3*2048*256
    float* yv     = ws + 16384 + 1572864;      // 3*2048*64
    float* dv_out = out + (size_t)BB * NN * NN * NN;

    k_pool    <<<dim3(BB),              dim3(256), 0, stream>>>(cond, cmask, pooled);
    k_dv      <<<dim3(DEGN * BB),       dim3(256), 0, stream>>>(pooled, Wc, dv, dv_out);
    k_enc     <<<dim3(DEGN * (BNR/16)), dim3(256), 0, stream>>>(x, W1, b1, dv, hbuf);
    k_lin     <<<dim3(DEGN * (BNR/16)), dim3(256), 0, stream>>>(hbuf, Wlin, blin, xmask, yv);
    k_contract<<<dim3(BNR),             dim3(256), 0, stream>>>(yv, out);
}

// Round 3
// 102.244 us; speedup vs baseline: 2.4861x; 1.1070x over previous
//
#include <hip/hip_runtime.h>
#include <hip/hip_bf16.h>
#include <math.h>
#include <string.h>

#define BB   16
#define NN   128
#define NCC  32
#define HH   256
#define AA   64
#define DEGN 3
#define BNR  (BB*NN)   // 2048 rows

typedef __bf16 bf16x8 __attribute__((ext_vector_type(8)));
typedef float  f32x4  __attribute__((ext_vector_type(4)));

// ---------------------------------------------------------------------------
// Kernel 1: masked mean-pool of condition vectors -> pooled [B,H]
// ---------------------------------------------------------------------------
__global__ __launch_bounds__(256) void k_pool(const float* __restrict__ cond,
                                              const float* __restrict__ cmask,
                                              float* __restrict__ pooled) {
    int b = blockIdx.x, h = threadIdx.x;
    float s = 0.f, ms = 0.f;
    for (int c = 0; c < NCC; ++c) {
        float mk = cmask[b * NCC + c];
        s  += cond[(b * NCC + c) * HH + h] * mk;
        ms += mk;
    }
    pooled[b * HH + h] = s / fmaxf(ms, 1.0f);
}

// ---------------------------------------------------------------------------
// Kernel 2: dv[d,b,:] = pooled[b,:] @ Wc[d]  (also writes dvs output)
// ---------------------------------------------------------------------------
__global__ __launch_bounds__(256) void k_dv(const float* __restrict__ pooled,
                                            const float* __restrict__ Wc,
                                            float* __restrict__ dv,
                                            float* __restrict__ dv_out) {
    int d = blockIdx.x / BB, b = blockIdx.x % BB, h = threadIdx.x;
    const float* Wd = Wc + (size_t)d * HH * HH;
    const float* pb = pooled + b * HH;
    float acc = 0.f;
    for (int k = 0; k < HH; ++k) acc += pb[k] * Wd[k * HH + h];
    int idx = (d * BB + b) * HH + h;
    dv[idx]     = acc;
    dv_out[idx] = acc;
}

// ---------------------------------------------------------------------------
// Kernel 3: hbuf[d,row,:] = gelu_tanh(x[row,:] @ W1[d] + b1[d] + dv[d,b])
// ---------------------------------------------------------------------------
__global__ __launch_bounds__(256) void k_enc(const float* __restrict__ x,
                                             const float* __restrict__ W1,
                                             const float* __restrict__ b1,
                                             const float* __restrict__ dv,
                                             float* __restrict__ hbuf) {
    const int RT = BNR / 16;  // 128 row-tiles
    int d = blockIdx.x / RT, rt = blockIdx.x % RT;
    int row0 = rt * 16;
    int h = threadIdx.x;
    __shared__ float xs[16][HH];
    #pragma unroll
    for (int rr = 0; rr < 16; ++rr) xs[rr][h] = x[(row0 + rr) * HH + h];
    __syncthreads();

    float acc[16];
    #pragma unroll
    for (int r = 0; r < 16; ++r) acc[r] = 0.f;

    const float* Wd = W1 + (size_t)d * HH * HH;
    for (int k = 0; k < HH; k += 4) {
        float w0 = Wd[(k + 0) * HH + h], w1 = Wd[(k + 1) * HH + h];
        float w2 = Wd[(k + 2) * HH + h], w3 = Wd[(k + 3) * HH + h];
        #pragma unroll
        for (int r = 0; r < 16; ++r) {
            float4 xv = *(const float4*)&xs[r][k];
            acc[r] += xv.x * w0 + xv.y * w1 + xv.z * w2 + xv.w * w3;
        }
    }
    int b = row0 / NN;
    float add = b1[d * HH + h] + dv[(d * BB + b) * HH + h];
    #pragma unroll
    for (int r = 0; r < 16; ++r) {
        float v = acc[r] + add;
        float u = 0.7978845608028654f * (v + 0.044715f * v * v * v);
        float g = 0.5f * v * (1.0f + tanhf(u));
        hbuf[((size_t)d * BNR + row0 + r) * HH + h] = g;
    }
}

// ---------------------------------------------------------------------------
// Kernel 4: yv[d,row,:] = (hbuf[d,row,:] @ Wlin[d] + blin[d]) * x_mask[row]
// ---------------------------------------------------------------------------
__global__ __launch_bounds__(256) void k_lin(const float* __restrict__ hbuf,
                                             const float* __restrict__ Wlin,
                                             const float* __restrict__ blin,
                                             const float* __restrict__ xmask,
                                             float* __restrict__ yv) {
    const int RT = BNR / 16;
    int d = blockIdx.x / RT, rt = blockIdx.x % RT;
    int row0 = rt * 16;
    int t = threadIdx.x;
    int a = t & 63, rg = t >> 6;
    __shared__ float hs[16][HH];
    for (int e = t; e < 16 * HH; e += 256) {
        int rr = e >> 8, k = e & 255;
        hs[rr][k] = hbuf[((size_t)d * BNR + row0 + rr) * HH + k];
    }
    __syncthreads();

    const float* Wd = Wlin + (size_t)d * HH * AA;
    float acc[4] = {0.f, 0.f, 0.f, 0.f};
    for (int k = 0; k < HH; k += 4) {
        float w0 = Wd[(k + 0) * AA + a], w1 = Wd[(k + 1) * AA + a];
        float w2 = Wd[(k + 2) * AA + a], w3 = Wd[(k + 3) * AA + a];
        #pragma unroll
        for (int rr = 0; rr < 4; ++rr) {
            float4 hv = *(const float4*)&hs[rg * 4 + rr][k];
            acc[rr] += hv.x * w0 + hv.y * w1 + hv.z * w2 + hv.w * w3;
        }
    }
    float bl = blin[d * AA + a];
    #pragma unroll
    for (int rr = 0; rr < 4; ++rr) {
        int row = row0 + rg * 4 + rr;
        yv[((size_t)d * BNR + row) * AA + a] = (acc[rr] + bl) * xmask[row];
    }
}

// ---------------------------------------------------------------------------
// Kernel 5: symmetric contraction via bf16 MFMA, transpose-free.
// out*4096 = A'B'^T + B'A'^T  (= P + P^T):
//   A'[r][k<64]  = s0[k]*Y1[r,k] + s1[k]*Y0[r,k];  A'[r][64+i] = s2[i]*Y0[r,i]
//   B'[r][k<64]  = Y2[r,k];                         B'[r][64+i] = Y1[r,i]
// LDS: two bf16 [128][128] tiles (32KB each), XOR-swizzled (byte ^= (row&7)<<4).
// Staging is lane-parallel: lane li covers cols 2li,2li+1 of a row; wave reads
// rows (r, r+1) as one contiguous 512B transaction; s-scalars via hoisted shfl.
// ---------------------------------------------------------------------------
__device__ __forceinline__ unsigned int pk2(float lo, float hi) {
    __hip_bfloat162 h2 = __float22bfloat162_rn(make_float2(lo, hi));
    unsigned int u;
    memcpy(&u, &h2, 4);
    return u;
}

__global__ __launch_bounds__(256) void k_contract(const float* __restrict__ yv,
                                                  float* __restrict__ outp) {
    __shared__ __align__(16) char lds[65536];  // A': [0,32K), B': [32K,64K)
    char* Albs = lds;
    char* Blbs = lds + 32768;

    const int t  = threadIdx.x;
    const int bx = blockIdx.x;            // b*N + x
    const int b  = bx >> 7, xr = bx & 127;

    const float* y0p = yv + (size_t)(0 * BNR + b * NN) * AA;
    const float* y1p = yv + (size_t)(1 * BNR + b * NN) * AA;
    const float* y2p = yv + (size_t)(2 * BNR + b * NN) * AA;

    const int lane = t & 63;
    const int wid  = t >> 6;
    // per-lane s values (each wave holds the full 64-vector across its lanes)
    const float s0 = y0p[xr * AA + lane];
    const float s1 = y1p[xr * AA + lane];
    const float s2 = y2p[xr * AA + lane];

    // ---- staging: each wave stages 32 rows of both A' and B' ----
    const int li = lane & 31;          // column-pair index
    const int rh = lane >> 5;          // row parity within the wave's pair
    const float s0a = __shfl(s0, 2 * li), s0b = __shfl(s0, 2 * li + 1);
    const float s1a = __shfl(s1, 2 * li), s1b = __shfl(s1, 2 * li + 1);
    const float s2a = __shfl(s2, 2 * li), s2b = __shfl(s2, 2 * li + 1);

    #pragma unroll
    for (int it = 0; it < 16; ++it) {
        const int r   = wid * 32 + it * 2 + rh;
        const int swz = (r & 7) << 4;
        const float2 v0 = *(const float2*)&y0p[r * AA + 2 * li];
        const float2 v1 = *(const float2*)&y1p[r * AA + 2 * li];
        const float2 v2 = *(const float2*)&y2p[r * AA + 2 * li];
        unsigned int a1 = pk2(s0a * v1.x + s1a * v0.x, s0b * v1.y + s1b * v0.y);
        unsigned int a2 = pk2(s2a * v0.x, s2b * v0.y);
        unsigned int b1 = pk2(v2.x, v2.y);
        unsigned int b2 = pk2(v1.x, v1.y);
        *(unsigned int*)(Albs + r * 256 + (( 4 * li      ) ^ swz)) = a1;
        *(unsigned int*)(Albs + r * 256 + ((128 + 4 * li ) ^ swz)) = a2;
        *(unsigned int*)(Blbs + r * 256 + (( 4 * li      ) ^ swz)) = b1;
        *(unsigned int*)(Blbs + r * 256 + ((128 + 4 * li ) ^ swz)) = b2;
    }
    __syncthreads();

    // ---- MFMA main loop: each wave computes a 64x64 output sub-tile ----
    const int wy = (wid >> 1) * 64, wz = (wid & 1) * 64;
    const int rl = lane & 15, hi = lane >> 4;

    f32x4 acc[4][4];
    #pragma unroll
    for (int mi = 0; mi < 4; ++mi)
        #pragma unroll
        for (int ni = 0; ni < 4; ++ni) {
            f32x4 z = {0.f, 0.f, 0.f, 0.f};
            acc[mi][ni] = z;
        }

    #pragma unroll
    for (int half = 0; half < 2; ++half) {
        const char* Ua = half ? Blbs : Albs;   // a-operand rows (y-range)
        const char* Vb = half ? Albs : Blbs;   // b-operand rows (z-range)
        #pragma unroll
        for (int ks = 0; ks < 4; ++ks) {
            bf16x8 af[4], bf[4];
            #pragma unroll
            for (int mi = 0; mi < 4; ++mi) {
                int row = wy + mi * 16 + rl;
                af[mi] = *(const bf16x8*)(Ua + row * 256 +
                          ((ks * 64 + hi * 16) ^ ((row & 7) << 4)));
            }
            #pragma unroll
            for (int ni = 0; ni < 4; ++ni) {
                int row = wz + ni * 16 + rl;
                bf[ni] = *(const bf16x8*)(Vb + row * 256 +
                          ((ks * 64 + hi * 16) ^ ((row & 7) << 4)));
            }
            #pragma unroll
            for (int mi = 0; mi < 4; ++mi)
                #pragma unroll
                for (int ni = 0; ni < 4; ++ni)
                    acc[mi][ni] = __builtin_amdgcn_mfma_f32_16x16x32_bf16(
                        af[mi], bf[ni], acc[mi][ni], 0, 0, 0);
        }
    }

    // ---- epilogue: scale and store (C/D layout: col=lane&15, row=hi*4+j) ----
    const float inv = 1.0f / 4096.0f;
    float* osl = outp + (size_t)bx * (NN * NN);
    #pragma unroll
    for (int mi = 0; mi < 4; ++mi) {
        #pragma unroll
        for (int ni = 0; ni < 4; ++ni) {
            int col   = wz + ni * 16 + rl;
            int rbase = wy + mi * 16 + hi * 4;
            #pragma unroll
            for (int j = 0; j < 4; ++j)
                osl[(rbase + j) * NN + col] = acc[mi][ni][j] * inv;
        }
    }
}

// ---------------------------------------------------------------------------
extern "C" void kernel_launch(void* const* d_in, const int* in_sizes, int n_in,
                              void* d_out, int out_size, void* d_ws, size_t ws_size,
                              hipStream_t stream) {
    const float* x     = (const float*)d_in[0];
    const float* xmask = (const float*)d_in[1];
    const float* cond  = (const float*)d_in[2];
    const float* cmask = (const float*)d_in[3];
    const float* W1    = (const float*)d_in[4];
    const float* b1    = (const float*)d_in[5];
    const float* Wc    = (const float*)d_in[6];
    const float* Wlin  = (const float*)d_in[7];
    const float* blin  = (const float*)d_in[8];

    float* out = (float*)d_out;
    float* ws  = (float*)d_ws;

    float* pooled = ws;                        // 16*256
    float* dv     = ws + 4096;                 // 3*16*256
    float* hbuf   = ws + 16384;                // 3*2048*256
    float* yv     = ws + 16384 + 1572864;      // 3*2048*64
    float* dv_out = out + (size_t)BB * NN * NN * NN;

    k_pool    <<<dim3(BB),              dim3(256), 0, stream>>>(cond, cmask, pooled);
    k_dv      <<<dim3(DEGN * BB),       dim3(256), 0, stream>>>(pooled, Wc, dv, dv_out);
    k_enc     <<<dim3(DEGN * (BNR/16)), dim3(256), 0, stream>>>(x, W1, b1, dv, hbuf);
    k_lin     <<<dim3(DEGN * (BNR/16)), dim3(256), 0, stream>>>(hbuf, Wlin, blin, xmask, yv);
    k_contract<<<dim3(BNR),             dim3(256), 0, stream>>>(yv, out);
}